// Round 1
// baseline (426.977 us; speedup 1.0000x reference)
//
#include <hip/hip_runtime.h>

// SCELoss: pred [N=8, C=19, H=512, W=1024] fp32, labels [8,512,1024] int32 (255 = ignore)
// out = 0.1 * CE + 1.0 * RCE_mean, scalar fp32.
//
// R5 (from R4 @ 401.2us): probe round.
//   - Roofline says ~53us (335.6 MB @ 6.3 TB/s); R4 ran at 13% of achievable BW.
//     No pipe (VALU/trans/MLP/coalescing) explains the gap in the model.
//   - Change 1: drop the nontemporal (nt) flag on the pred/label loads. Streaming
//     318 MB has no L2 reuse either way, so nt is ~free if innocent; if gfx950's
//     nt path degrades the load pipe it is a uniform multiplier — exactly the
//     observed flat slowdown shape.
//   - Change 2: p_y = exp(x_y - log s) reusing the CE log(s) instead of
//     exp(x_y)/s (saves rcp+mul per pixel; x_y <= log s so p_y <= 1 exactly).
// Structure otherwise identical to R4: storage-free streaming softmax,
// 4 px/thread, ~30 VGPR -> 8 waves/SIMD, per-block partials, no atomics.

#define NCLS 19
#define HW (512 * 1024)        // 2^19
#define NPIX (8 * HW)          // 4,194,304 pixels
#define IGNORE_L 255
#define GRID_MAIN 4096         // (NPIX/4) / 256

typedef float f32x4 __attribute__((ext_vector_type(4)));
typedef int   i32x4 __attribute__((ext_vector_type(4)));

static constexpr float NEG_LOG_OH = 9.210340371976184f;  // -log(1e-4)
static constexpr float P_MIN_F = 1e-7f;

__global__ __launch_bounds__(256) void sce_main(const float* __restrict__ pred,
                                                const int* __restrict__ labels,
                                                float* __restrict__ ws) {
    const int t = blockIdx.x * 256 + threadIdx.x;
    const int p0 = t * 4;  // 4 consecutive pixels per thread

    const int n = p0 >> 19;           // batch index (HW = 2^19)
    const int hw = p0 & (HW - 1);
    const float* base = pred + ((size_t)n * NCLS) * (size_t)HW + (size_t)hw;

    const i32x4 labv = *(const i32x4*)(labels + p0);

    // Four independent accumulation chains (ILP); loads pipelined by compiler.
    float s0 = 0.0f, s1 = 0.0f, s2 = 0.0f, s3 = 0.0f;
    float xy0 = 0.0f, xy1 = 0.0f, xy2 = 0.0f, xy3 = 0.0f;
    #pragma unroll
    for (int c = 0; c < NCLS; ++c) {
        const f32x4 v = *(const f32x4*)(base + (size_t)c * HW);
        s0 += __expf(v.x); if (labv.x == c) xy0 = v.x;
        s1 += __expf(v.y); if (labv.y == c) xy1 = v.y;
        s2 += __expf(v.z); if (labv.z == c) xy2 = v.z;
        s3 += __expf(v.w); if (labv.w == c) xy3 = v.w;
    }

    float ce_acc = 0.0f, rce_acc = 0.0f, cnt = 0.0f;
    {
        const float ls0 = __logf(s0);
        const float ls1 = __logf(s1);
        const float ls2 = __logf(s2);
        const float ls3 = __logf(s3);
        // x_y <= log(s) always, so exp(x_y - log s) <= 1; clamp only the floor.
        const float py0 = fmaxf(__expf(xy0 - ls0), P_MIN_F);
        const float py1 = fmaxf(__expf(xy1 - ls1), P_MIN_F);
        const float py2 = fmaxf(__expf(xy2 - ls2), P_MIN_F);
        const float py3 = fmaxf(__expf(xy3 - ls3), P_MIN_F);
        if (labv.x != IGNORE_L) { ce_acc += ls0 - xy0; rce_acc += 1.0f - py0; cnt += 1.0f; }
        if (labv.y != IGNORE_L) { ce_acc += ls1 - xy1; rce_acc += 1.0f - py1; cnt += 1.0f; }
        if (labv.z != IGNORE_L) { ce_acc += ls2 - xy2; rce_acc += 1.0f - py2; cnt += 1.0f; }
        if (labv.w != IGNORE_L) { ce_acc += ls3 - xy3; rce_acc += 1.0f - py3; cnt += 1.0f; }
    }

    // Wave-64 reduction.
    #pragma unroll
    for (int off = 32; off > 0; off >>= 1) {
        ce_acc  += __shfl_down(ce_acc, off);
        rce_acc += __shfl_down(rce_acc, off);
        cnt     += __shfl_down(cnt, off);
    }

    // Block reduction (4 waves), per-block partial write (no atomics).
    __shared__ float red_ce[4], red_rce[4], red_cnt[4];
    const int wave = threadIdx.x >> 6;
    const int lane = threadIdx.x & 63;
    if (lane == 0) { red_ce[wave] = ce_acc; red_rce[wave] = rce_acc; red_cnt[wave] = cnt; }
    __syncthreads();
    if (threadIdx.x == 0) {
        const int b = blockIdx.x;
        ws[b]               = red_ce[0] + red_ce[1] + red_ce[2] + red_ce[3];
        ws[GRID_MAIN + b]   = red_rce[0] + red_rce[1] + red_rce[2] + red_rce[3];
        ws[2*GRID_MAIN + b] = red_cnt[0] + red_cnt[1] + red_cnt[2] + red_cnt[3];
    }
}

__global__ __launch_bounds__(256) void sce_finalize(const float* __restrict__ ws,
                                                    float* __restrict__ out) {
    float ce = 0.0f, rce = 0.0f, cnt = 0.0f;
    for (int i = threadIdx.x; i < GRID_MAIN; i += 256) {
        ce  += ws[i];
        rce += ws[GRID_MAIN + i];
        cnt += ws[2*GRID_MAIN + i];
    }
    #pragma unroll
    for (int off = 32; off > 0; off >>= 1) {
        ce  += __shfl_down(ce, off);
        rce += __shfl_down(rce, off);
        cnt += __shfl_down(cnt, off);
    }
    __shared__ float red_ce[4], red_rce[4], red_cnt[4];
    const int wave = threadIdx.x >> 6;
    const int lane = threadIdx.x & 63;
    if (lane == 0) { red_ce[wave] = ce; red_rce[wave] = rce; red_cnt[wave] = cnt; }
    __syncthreads();
    if (threadIdx.x == 0) {
        const float tce  = red_ce[0] + red_ce[1] + red_ce[2] + red_ce[3];
        const float trce = red_rce[0] + red_rce[1] + red_rce[2] + red_rce[3];
        const float tcnt = red_cnt[0] + red_cnt[1] + red_cnt[2] + red_cnt[3];
        out[0] = 0.1f * (tce / tcnt) + NEG_LOG_OH * (trce / tcnt);
    }
}

extern "C" void kernel_launch(void* const* d_in, const int* in_sizes, int n_in,
                              void* d_out, int out_size, void* d_ws, size_t ws_size,
                              hipStream_t stream) {
    const float* pred = (const float*)d_in[0];
    const int* labels = (const int*)d_in[1];
    float* ws = (float*)d_ws;
    float* out = (float*)d_out;

    sce_main<<<GRID_MAIN, 256, 0, stream>>>(pred, labels, ws);
    sce_finalize<<<1, 256, 0, stream>>>(ws, out);
}

// Round 3
// 402.309 us; speedup vs baseline: 1.0613x; 1.0613x over previous
//
#include <hip/hip_runtime.h>

// SCELoss: pred [N=8, C=19, H=512, W=1024] fp32, labels [8,512,1024] int32 (255 = ignore)
// out = 0.1 * CE + 1.0 * RCE_mean, scalar fp32.
//
// R7 = R6 resubmitted verbatim (R6 bench failed: GPU acquisition timeout).
// R6 rationale (from R5 @ 427.0us, R4 @ 401.2us):
//   Counter finding: top-5 dispatches are ALL harness fillBufferAligned
//   (1.275 GB poison writes @ ~190us, 6.5-6.7 TB/s). sce_main < 190us and
//   never appears. Measured dur_us is fill-dominated; kernel share is either
//   ~47us (2 fills/iter -> already at the 335.6MB read roofline) or ~237us
//   (1 fill/iter -> latency-limited). This round disambiguates while being
//   the best-shot fix for the latter:
//   - revert to nontemporal loads (only diff vs the 401.2 best),
//   - keep py = exp(x_y - log s) (reuses CE's log, saves rcp+mul),
//   - 8 px/thread as TWO independent fully-coalesced 1KB streams per class
//     (chunk A @ tid*4, chunk B @ +1024): 2x outstanding loads per wave,
//     half the blocks (2048), half the loop/reduction overhead per byte.
//   If dur_us is unchanged (~400-430): kernel is roofline-resident, done.

#define NCLS 19
#define HW (512 * 1024)        // 2^19
#define NPIX (8 * HW)          // 4,194,304 pixels
#define IGNORE_L 255
#define PIX_PER_BLOCK 2048     // 256 threads * 8 px
#define GRID_MAIN (NPIX / PIX_PER_BLOCK)   // 2048

typedef float f32x4 __attribute__((ext_vector_type(4)));
typedef int   i32x4 __attribute__((ext_vector_type(4)));

static constexpr float NEG_LOG_OH = 9.210340371976184f;  // -log(1e-4)
static constexpr float P_MIN_F = 1e-7f;

__global__ __launch_bounds__(256) void sce_main(const float* __restrict__ pred,
                                                const int* __restrict__ labels,
                                                float* __restrict__ ws) {
    // Chunk A: pixels [p0, p0+3]; chunk B: pixels [p0+1024, p0+1027].
    // Both 1KB-contiguous per wave-load (64 lanes x 16B), both inside the
    // same batch row n (PIX_PER_BLOCK=2048 divides HW).
    const int p0 = blockIdx.x * PIX_PER_BLOCK + threadIdx.x * 4;

    const int n = p0 >> 19;           // batch index (HW = 2^19)
    const int hw = p0 & (HW - 1);
    const float* baseA = pred + ((size_t)n * NCLS) * (size_t)HW + (size_t)hw;
    const float* baseB = baseA + 1024;

    const i32x4 labA = __builtin_nontemporal_load((const i32x4*)(labels + p0));
    const i32x4 labB = __builtin_nontemporal_load((const i32x4*)(labels + p0 + 1024));

    // Eight independent accumulation chains (ILP); loads pipelined by compiler.
    float sa0 = 0.0f, sa1 = 0.0f, sa2 = 0.0f, sa3 = 0.0f;
    float sb0 = 0.0f, sb1 = 0.0f, sb2 = 0.0f, sb3 = 0.0f;
    float xa0 = 0.0f, xa1 = 0.0f, xa2 = 0.0f, xa3 = 0.0f;
    float xb0 = 0.0f, xb1 = 0.0f, xb2 = 0.0f, xb3 = 0.0f;
    #pragma unroll
    for (int c = 0; c < NCLS; ++c) {
        const f32x4 va = __builtin_nontemporal_load((const f32x4*)(baseA + (size_t)c * HW));
        const f32x4 vb = __builtin_nontemporal_load((const f32x4*)(baseB + (size_t)c * HW));
        sa0 += __expf(va.x); if (labA.x == c) xa0 = va.x;
        sa1 += __expf(va.y); if (labA.y == c) xa1 = va.y;
        sa2 += __expf(va.z); if (labA.z == c) xa2 = va.z;
        sa3 += __expf(va.w); if (labA.w == c) xa3 = va.w;
        sb0 += __expf(vb.x); if (labB.x == c) xb0 = vb.x;
        sb1 += __expf(vb.y); if (labB.y == c) xb1 = vb.y;
        sb2 += __expf(vb.z); if (labB.z == c) xb2 = vb.z;
        sb3 += __expf(vb.w); if (labB.w == c) xb3 = vb.w;
    }

    float ce_acc = 0.0f, rce_acc = 0.0f, cnt = 0.0f;
    {
        const float la0 = __logf(sa0), la1 = __logf(sa1), la2 = __logf(sa2), la3 = __logf(sa3);
        const float lb0 = __logf(sb0), lb1 = __logf(sb1), lb2 = __logf(sb2), lb3 = __logf(sb3);
        // x_y <= log(s) always, so exp(x_y - log s) <= 1; clamp only the floor.
        const float pa0 = fmaxf(__expf(xa0 - la0), P_MIN_F);
        const float pa1 = fmaxf(__expf(xa1 - la1), P_MIN_F);
        const float pa2 = fmaxf(__expf(xa2 - la2), P_MIN_F);
        const float pa3 = fmaxf(__expf(xa3 - la3), P_MIN_F);
        const float pb0 = fmaxf(__expf(xb0 - lb0), P_MIN_F);
        const float pb1 = fmaxf(__expf(xb1 - lb1), P_MIN_F);
        const float pb2 = fmaxf(__expf(xb2 - lb2), P_MIN_F);
        const float pb3 = fmaxf(__expf(xb3 - lb3), P_MIN_F);
        if (labA.x != IGNORE_L) { ce_acc += la0 - xa0; rce_acc += 1.0f - pa0; cnt += 1.0f; }
        if (labA.y != IGNORE_L) { ce_acc += la1 - xa1; rce_acc += 1.0f - pa1; cnt += 1.0f; }
        if (labA.z != IGNORE_L) { ce_acc += la2 - xa2; rce_acc += 1.0f - pa2; cnt += 1.0f; }
        if (labA.w != IGNORE_L) { ce_acc += la3 - xa3; rce_acc += 1.0f - pa3; cnt += 1.0f; }
        if (labB.x != IGNORE_L) { ce_acc += lb0 - xb0; rce_acc += 1.0f - pb0; cnt += 1.0f; }
        if (labB.y != IGNORE_L) { ce_acc += lb1 - xb1; rce_acc += 1.0f - pb1; cnt += 1.0f; }
        if (labB.z != IGNORE_L) { ce_acc += lb2 - xb2; rce_acc += 1.0f - pb2; cnt += 1.0f; }
        if (labB.w != IGNORE_L) { ce_acc += lb3 - xb3; rce_acc += 1.0f - pb3; cnt += 1.0f; }
    }

    // Wave-64 reduction.
    #pragma unroll
    for (int off = 32; off > 0; off >>= 1) {
        ce_acc  += __shfl_down(ce_acc, off);
        rce_acc += __shfl_down(rce_acc, off);
        cnt     += __shfl_down(cnt, off);
    }

    // Block reduction (4 waves), per-block partial write (no atomics).
    __shared__ float red_ce[4], red_rce[4], red_cnt[4];
    const int wave = threadIdx.x >> 6;
    const int lane = threadIdx.x & 63;
    if (lane == 0) { red_ce[wave] = ce_acc; red_rce[wave] = rce_acc; red_cnt[wave] = cnt; }
    __syncthreads();
    if (threadIdx.x == 0) {
        const int b = blockIdx.x;
        ws[b]               = red_ce[0] + red_ce[1] + red_ce[2] + red_ce[3];
        ws[GRID_MAIN + b]   = red_rce[0] + red_rce[1] + red_rce[2] + red_rce[3];
        ws[2*GRID_MAIN + b] = red_cnt[0] + red_cnt[1] + red_cnt[2] + red_cnt[3];
    }
}

__global__ __launch_bounds__(256) void sce_finalize(const float* __restrict__ ws,
                                                    float* __restrict__ out) {
    float ce = 0.0f, rce = 0.0f, cnt = 0.0f;
    for (int i = threadIdx.x; i < GRID_MAIN; i += 256) {
        ce  += ws[i];
        rce += ws[GRID_MAIN + i];
        cnt += ws[2*GRID_MAIN + i];
    }
    #pragma unroll
    for (int off = 32; off > 0; off >>= 1) {
        ce  += __shfl_down(ce, off);
        rce += __shfl_down(rce, off);
        cnt += __shfl_down(cnt, off);
    }
    __shared__ float red_ce[4], red_rce[4], red_cnt[4];
    const int wave = threadIdx.x >> 6;
    const int lane = threadIdx.x & 63;
    if (lane == 0) { red_ce[wave] = ce; red_rce[wave] = rce; red_cnt[wave] = cnt; }
    __syncthreads();
    if (threadIdx.x == 0) {
        const float tce  = red_ce[0] + red_ce[1] + red_ce[2] + red_ce[3];
        const float trce = red_rce[0] + red_rce[1] + red_rce[2] + red_rce[3];
        const float tcnt = red_cnt[0] + red_cnt[1] + red_cnt[2] + red_cnt[3];
        out[0] = 0.1f * (tce / tcnt) + NEG_LOG_OH * (trce / tcnt);
    }
}

extern "C" void kernel_launch(void* const* d_in, const int* in_sizes, int n_in,
                              void* d_out, int out_size, void* d_ws, size_t ws_size,
                              hipStream_t stream) {
    const float* pred = (const float*)d_in[0];
    const int* labels = (const int*)d_in[1];
    float* ws = (float*)d_ws;
    float* out = (float*)d_out;

    sce_main<<<GRID_MAIN, 256, 0, stream>>>(pred, labels, ws);
    sce_finalize<<<1, 256, 0, stream>>>(ws, out);
}